// Round 1
// baseline (211.753 us; speedup 1.0000x reference)
//
#include <hip/hip_runtime.h>
#include <math.h>

typedef unsigned short u16;
typedef __attribute__((ext_vector_type(8))) _Float16 half8;    // 8 fp16
typedef __attribute__((ext_vector_type(4))) float    f32x4;

#define BATCH 4
#define NPB   4096      // pixels per batch (H*W)
#define BN    16384     // BATCH * NPB
#define CC    256       // input channels
#define D     128       // output channels (C/2)
#define LOG2E 1.44269504088896f
#define THR   8.0f      // deferred-rescale threshold (exp2 domain; P <= 256 in fp16)

#if __has_builtin(__builtin_amdgcn_exp2f)
#define EXP2(x) __builtin_amdgcn_exp2f(x)
#else
#define EXP2(x) exp2f(x)
#endif

// 16-lane (DPP row) reductions on the VALU pipe — no LDS crossbar.
template<int CTRL>
__device__ __forceinline__ float dpp_mov(float x) {
    return __builtin_bit_cast(float, __builtin_amdgcn_update_dpp(
        __builtin_bit_cast(int, x), __builtin_bit_cast(int, x),
        CTRL, 0xf, 0xf, false));
}
__device__ __forceinline__ float dpp_row_max(float x) {
    x = fmaxf(x, dpp_mov<0x128>(x));   // row_ror:8
    x = fmaxf(x, dpp_mov<0x124>(x));   // row_ror:4
    x = fmaxf(x, dpp_mov<0x122>(x));   // row_ror:2
    x = fmaxf(x, dpp_mov<0x121>(x));   // row_ror:1
    return x;
}
__device__ __forceinline__ float dpp_row_sum(float x) {
    x += dpp_mov<0x128>(x);
    x += dpp_mov<0x124>(x);
    x += dpp_mov<0x122>(x);
    x += dpp_mov<0x121>(x);
    return x;
}

// ---------------------------------------------------------------------------
// Prep: W[mat] (f32 [256][128]) -> Wt[mat][c][k] fp16 (c-major, contiguous k).
// mat 0 (K) pre-scaled by log2e. 128 blocks x 256 threads x 4 elements.
// ---------------------------------------------------------------------------
__global__ __launch_bounds__(256) void prep_kernel(
    const float* __restrict__ Wk, const float* __restrict__ Wq,
    const float* __restrict__ Wv, const float* __restrict__ Ws,
    u16* __restrict__ Wt)
{
    const int f   = (blockIdx.x * 256 + threadIdx.x) * 4;   // flat output idx
    const int mat = f >> 15;
    const int rem = f & 32767;
    const int c   = rem >> 8;
    const int k0  = rem & 255;
    const float* W = (mat == 0) ? Wk : (mat == 1) ? Wq : (mat == 2) ? Wv : Ws;
    const float scale = (mat == 0) ? LOG2E : 1.0f;
    _Float16 t4[4];
#pragma unroll
    for (int i = 0; i < 4; ++i)
        t4[i] = (_Float16)(W[(size_t)(k0 + i) * D + c] * scale);
    *(uint2*)&Wt[(size_t)mat * 32768 + (size_t)c * 256 + k0] = *(const uint2*)t4;
}

// ---------------------------------------------------------------------------
// Projection: grid (128, 4) = 128-pixel x-tile x one matrix per block.
// (unchanged from previous round — not the bottleneck this round)
// ---------------------------------------------------------------------------
#define APJ 264         // As row pitch in u16 (528 B: 16B-aligned, 4-bank row shift)

__global__ __launch_bounds__(256, 2) void proj_kernel(
    const float* __restrict__ x, const u16* __restrict__ Wt,
    const float* __restrict__ bk, const float* __restrict__ bq,
    const float* __restrict__ bv, const float* __restrict__ bs,
    u16* __restrict__ Kh, u16* __restrict__ Qh,
    u16* __restrict__ Vt, float* __restrict__ Sc)
{
    __shared__ __align__(16) u16 As[128][APJ];   // 66 KB -> 2 blocks/CU

    const int tid = threadIdx.x;
    const int wv  = tid >> 6;
    const int l   = tid & 63;
    const int l15 = l & 15;
    const int l4  = l >> 4;
    const int by  = blockIdx.y;
    const int gm0 = blockIdx.x * 128;
    const int c0  = wv * 32;

    // ---- W fragments from Wt: wf[ct][kc], lane -> W[k=kc*32+l4*8..+8][c0+ct*16+l15]
    const u16* wb = Wt + (size_t)by * 32768 + (size_t)(c0 + l15) * 256 + l4 * 8;
    half8 wf[2][8];
#pragma unroll
    for (int ct = 0; ct < 2; ++ct)
#pragma unroll
        for (int kc = 0; kc < 8; ++kc)
            wf[ct][kc] = *(const half8*)(wb + ct * 16 * 256 + kc * 32);

    // ---- stage the 128x256 x-tile once (coalesced: thread t -> float4 i*256+t)
    {
        const float4* xg = (const float4*)(x + (size_t)gm0 * CC);
#pragma unroll 8
        for (int i = 0; i < 32; ++i) {
            const int f = i * 256 + tid;           // flat float4 index
            const float4 v = xg[f];
            const int row = f >> 6, col4 = f & 63;
            _Float16 h[4] = {(_Float16)v.x, (_Float16)v.y,
                             (_Float16)v.z, (_Float16)v.w};
            *(uint2*)&As[row][col4 * 4] = *(const uint2*)h;
        }
    }
    __syncthreads();

    f32x4 acc[8][2];
#pragma unroll
    for (int mt = 0; mt < 8; ++mt) {
        acc[mt][0] = (f32x4){0.f, 0.f, 0.f, 0.f};
        acc[mt][1] = (f32x4){0.f, 0.f, 0.f, 0.f};
    }

    if (by == 2) {
        for (int kc = 0; kc < 8; ++kc)
#pragma unroll
            for (int mt = 0; mt < 8; ++mt) {
                const half8 a = *(const half8*)&As[mt * 16 + l15][kc * 32 + l4 * 8];
                acc[mt][0] = __builtin_amdgcn_mfma_f32_16x16x32_f16(a, wf[0][kc], acc[mt][0], 0, 0, 0);
                acc[mt][1] = __builtin_amdgcn_mfma_f32_16x16x32_f16(a, wf[1][kc], acc[mt][1], 0, 0, 0);
            }
        // V: D[m][c]; fp16 transposed [batch][c][m], pack 4 consecutive m
        const float bb[2] = {bv[c0 + l15], bv[c0 + 16 + l15]};
        const int batch = gm0 >> 12;
        const int mb0   = (gm0 & 4095) + l4 * 4;
        u16* vbp = Vt + (size_t)batch * (D * NPB);
#pragma unroll
        for (int mt = 0; mt < 8; ++mt)
#pragma unroll
            for (int ct = 0; ct < 2; ++ct) {
                const int c = c0 + ct * 16 + l15;
                _Float16 t4[4];
#pragma unroll
                for (int r = 0; r < 4; ++r)
                    t4[r] = (_Float16)(acc[mt][ct][r] + bb[ct]);
                *(uint2*)&vbp[(size_t)c * NPB + mb0 + mt * 16] = *(const uint2*)t4;
            }
    } else {
        for (int kc = 0; kc < 8; ++kc)
#pragma unroll
            for (int mt = 0; mt < 8; ++mt) {
                const half8 a = *(const half8*)&As[mt * 16 + l15][kc * 32 + l4 * 8];
                acc[mt][0] = __builtin_amdgcn_mfma_f32_16x16x32_f16(wf[0][kc], a, acc[mt][0], 0, 0, 0);
                acc[mt][1] = __builtin_amdgcn_mfma_f32_16x16x32_f16(wf[1][kc], a, acc[mt][1], 0, 0, 0);
            }
        // swapped: D[c][m] — lane holds c = c0+ct*16+l4*4+r, m = gm0+mt*16+l15
        if (by == 3) {
            float bb2[2][4];
#pragma unroll
            for (int ct = 0; ct < 2; ++ct)
#pragma unroll
                for (int r = 0; r < 4; ++r)
                    bb2[ct][r] = bs[c0 + ct * 16 + l4 * 4 + r];
#pragma unroll
            for (int mt = 0; mt < 8; ++mt) {
                const int m = gm0 + mt * 16 + l15;
#pragma unroll
                for (int ct = 0; ct < 2; ++ct) {
                    float4 v;
                    v.x = acc[mt][ct][0] + bb2[ct][0];
                    v.y = acc[mt][ct][1] + bb2[ct][1];
                    v.z = acc[mt][ct][2] + bb2[ct][2];
                    v.w = acc[mt][ct][3] + bb2[ct][3];
                    *(float4*)&Sc[(size_t)m * D + c0 + ct * 16 + l4 * 4] = v;
                }
            }
        } else {
            const float* bsrc = (by == 0) ? bk : bq;
            const float scale = (by == 0) ? LOG2E : 1.0f;   // Wt already scaled
            u16* O = (by == 0) ? Kh : Qh;
            float bb2[2][4];
#pragma unroll
            for (int ct = 0; ct < 2; ++ct)
#pragma unroll
                for (int r = 0; r < 4; ++r)
                    bb2[ct][r] = bsrc[c0 + ct * 16 + l4 * 4 + r] * scale;
#pragma unroll
            for (int mt = 0; mt < 8; ++mt) {
                const int m = gm0 + mt * 16 + l15;
#pragma unroll
                for (int ct = 0; ct < 2; ++ct) {
                    _Float16 t4[4];
#pragma unroll
                    for (int r = 0; r < 4; ++r)
                        t4[r] = (_Float16)(acc[mt][ct][r] + bb2[ct][r]);
                    *(uint2*)&O[(size_t)m * D + c0 + ct * 16 + l4 * 4] =
                        *(const uint2*)t4;
                }
            }
        }
    }
}

// ---------------------------------------------------------------------------
// Flash attention v2: barrier-free main loop, global->register fragments.
// 512 blocks x 32 n-rows; 4 waves = 4 disjoint m-quarters (1024 m each,
// 32 iters x 32 m). K/Q/V fragments loaded straight from global (L2-resident,
// XCD-affinity swizzle keeps one batch per XCD pair). LDS only for the
// wave-private P transpose + the one-time 4-way merge. Deferred rescale
// (THR=8, exp2 domain). Next-iter fragments issued right after current ones
// are consumed -> L2 latency hides under softmax/MFMA.
// ---------------------------------------------------------------------------
#define VP  40          // Ps row pitch (u16)
#define OBP 132         // Obuf row pitch (f32): 528 B, 16B-aligned, bank shift 4

__global__ __launch_bounds__(256, 2) void attn_kernel(
    const u16* __restrict__ Kh, const u16* __restrict__ Qh,
    const u16* __restrict__ Vt, const float* __restrict__ Sc,
    float* __restrict__ out)
{
    __shared__ __align__(16) unsigned char smem[4 * 32 * OBP * 4 + 1024]; // 68.6 KB
    u16   (*Ps)[32][VP]    = (u16(*)[32][VP])(smem);              // aliases Obuf
    float (*Obuf)[32][OBP] = (float(*)[32][OBP])(smem);
    float (*ml)[2][32]     = (float(*)[2][32])(smem + 4 * 32 * OBP * 4);

    const int tid = threadIdx.x;
    const int wv  = tid >> 6;
    const int l   = tid & 63;
    const int l15 = l & 15;
    const int l4  = l >> 4;

    // XCD-affinity remap (bijective on [0,512)): round-robin dispatch puts
    // bx%8 on XCD bx%8 -> each XCD pair serves exactly one batch (Q+V+K ~ 3MB
    // working set fits the 4 MB per-XCD L2).
    const int bx    = blockIdx.x;
    const int xcd   = bx & 7;
    const int batch = xcd >> 1;
    const int tile  = ((xcd & 1) << 6) | (bx >> 3);
    const int gr0   = batch * NPB + tile * 32;      // this block's 32 K-rows

    // ---- K fragments straight from global (log2e pre-scaled), held all loop
    half8 kf[2][4];
    {
        const u16* kb = Kh + (size_t)(gr0 + l15) * D + l4 * 8;
#pragma unroll
        for (int nt = 0; nt < 2; ++nt)
#pragma unroll
            for (int kc = 0; kc < 4; ++kc)
                kf[nt][kc] = *(const half8*)(kb + (size_t)nt * 16 * D + kc * 32);
    }

    // ---- per-wave m-quarter pointers
    const int mq0 = batch * NPB + wv * 1024;
    const u16* qp = Qh + (size_t)(mq0 + l15) * D + l4 * 8;
    const u16* vp = Vt + (size_t)batch * NPB * D + (size_t)l15 * NPB
                    + wv * 1024 + l4 * 8;

    // ---- prologue fragment loads (it = 0)
    half8 qf[2][4], vf[8];
#pragma unroll
    for (int mt = 0; mt < 2; ++mt)
#pragma unroll
        for (int kc = 0; kc < 4; ++kc)
            qf[mt][kc] = *(const half8*)(qp + (size_t)mt * 16 * D + kc * 32);
#pragma unroll
    for (int ct = 0; ct < 8; ++ct)
        vf[ct] = *(const half8*)(vp + (size_t)ct * 16 * NPB);

    f32x4 Oc[2][8];
#pragma unroll
    for (int nt = 0; nt < 2; ++nt)
#pragma unroll
        for (int ct = 0; ct < 8; ++ct)
            Oc[nt][ct] = (f32x4){0.f, 0.f, 0.f, 0.f};
    float mold[2][4], lsum[2][4];
#pragma unroll
    for (int nt = 0; nt < 2; ++nt)
#pragma unroll
        for (int r = 0; r < 4; ++r) { mold[nt][r] = -1e30f; lsum[nt][r] = 0.f; }

    for (int it = 0; it < 32; ++it) {
        // ---- S' = (K*log2e) @ Q^T : 32n x 32m, exp2 domain
        f32x4 sacc[2][2];
        sacc[0][0] = (f32x4){0.f, 0.f, 0.f, 0.f};
        sacc[0][1] = (f32x4){0.f, 0.f, 0.f, 0.f};
        sacc[1][0] = (f32x4){0.f, 0.f, 0.f, 0.f};
        sacc[1][1] = (f32x4){0.f, 0.f, 0.f, 0.f};
        __builtin_amdgcn_s_setprio(1);
#pragma unroll
        for (int kc = 0; kc < 4; ++kc)
#pragma unroll
            for (int nt = 0; nt < 2; ++nt)
#pragma unroll
                for (int mt = 0; mt < 2; ++mt)
                    sacc[nt][mt] = __builtin_amdgcn_mfma_f32_16x16x32_f16(
                        kf[nt][kc], qf[mt][kc], sacc[nt][mt], 0, 0, 0);
        __builtin_amdgcn_s_setprio(0);

        // ---- issue next Q tile now (latency hides under softmax + PV)
        qp += 32 * D;
        if (it < 31) {
#pragma unroll
            for (int mt = 0; mt < 2; ++mt)
#pragma unroll
                for (int kc = 0; kc < 4; ++kc)
                    qf[mt][kc] = *(const half8*)(qp + (size_t)mt * 16 * D + kc * 32);
        }

        // ---- online softmax with deferred rescale (T13)
        float rmax[2][4];
        int grow = 0;
#pragma unroll
        for (int nt = 0; nt < 2; ++nt)
#pragma unroll
            for (int r = 0; r < 4; ++r) {
                rmax[nt][r] = dpp_row_max(fmaxf(sacc[nt][0][r], sacc[nt][1][r]));
                grow |= (rmax[nt][r] > mold[nt][r] + THR) ? 1 : 0;
            }
        if (__any(grow)) {
#pragma unroll
            for (int nt = 0; nt < 2; ++nt)
#pragma unroll
                for (int r = 0; r < 4; ++r) {
                    const float mnew  = fmaxf(mold[nt][r], rmax[nt][r]);
                    const float alpha = EXP2(mold[nt][r] - mnew);
                    mold[nt][r] = mnew;
                    lsum[nt][r] *= alpha;
#pragma unroll
                    for (int ct = 0; ct < 8; ++ct)
                        Oc[nt][ct][r] *= alpha;
                }
        }
#pragma unroll
        for (int nt = 0; nt < 2; ++nt)
#pragma unroll
            for (int r = 0; r < 4; ++r) {
                const float p0 = EXP2(sacc[nt][0][r] - mold[nt][r]);
                const float p1 = EXP2(sacc[nt][1][r] - mold[nt][r]);
                lsum[nt][r] += p0 + p1;
                const int row = nt * 16 + l4 * 4 + r;
                Ps[wv][row][l15]      = __builtin_bit_cast(u16, (_Float16)p0);
                Ps[wv][row][16 + l15] = __builtin_bit_cast(u16, (_Float16)p1);
            }
        asm volatile("s_waitcnt lgkmcnt(0)" ::: "memory");   // wave-private Ps

        // ---- PV: O += P @ V
        const half8 pf0 = *(const half8*)&Ps[wv][l15][l4 * 8];
        const half8 pf1 = *(const half8*)&Ps[wv][16 + l15][l4 * 8];
        __builtin_amdgcn_s_setprio(1);
#pragma unroll
        for (int ct = 0; ct < 8; ++ct) {
            Oc[0][ct] = __builtin_amdgcn_mfma_f32_16x16x32_f16(pf0, vf[ct], Oc[0][ct], 0, 0, 0);
            Oc[1][ct] = __builtin_amdgcn_mfma_f32_16x16x32_f16(pf1, vf[ct], Oc[1][ct], 0, 0, 0);
        }
        __builtin_amdgcn_s_setprio(0);

        // ---- issue next V tile (latency hides under next QK + softmax)
        vp += 32;
        if (it < 31) {
#pragma unroll
            for (int ct = 0; ct < 8; ++ct)
                vf[ct] = *(const half8*)(vp + (size_t)ct * 16 * NPB);
        }
    }

    // ---- full row sums across the 16 column-lanes (once, DPP)
#pragma unroll
    for (int nt = 0; nt < 2; ++nt)
#pragma unroll
        for (int r = 0; r < 4; ++r)
            lsum[nt][r] = dpp_row_sum(lsum[nt][r]);

    // ---- publish per-wave (m, l) per row
    if (l15 == 0) {
#pragma unroll
        for (int nt = 0; nt < 2; ++nt)
#pragma unroll
            for (int r = 0; r < 4; ++r) {
                const int row = nt * 16 + l4 * 4 + r;
                ml[wv][0][row] = mold[nt][r];
                ml[wv][1][row] = lsum[nt][r];
            }
    }
    __syncthreads();                      // ml visible; Ps region now dead

    // ---- scale own partial into common max-frame, write to Obuf
#pragma unroll
    for (int nt = 0; nt < 2; ++nt)
#pragma unroll
        for (int r = 0; r < 4; ++r) {
            const int row = nt * 16 + l4 * 4 + r;
            const float M = fmaxf(fmaxf(ml[0][0][row], ml[1][0][row]),
                                  fmaxf(ml[2][0][row], ml[3][0][row]));
            const float f = EXP2(mold[nt][r] - M);
#pragma unroll
            for (int ct = 0; ct < 8; ++ct)
                Obuf[wv][row][ct * 16 + l15] = Oc[nt][ct][r] * f;
        }
    __syncthreads();

    // ---- 4-way merge: wave wv handles rows [wv*8, wv*8+8), 8 lanes/row
    {
        const int row = wv * 8 + (l >> 3);
        const int c0  = (l & 7) * 16;
        const float M = fmaxf(fmaxf(ml[0][0][row], ml[1][0][row]),
                              fmaxf(ml[2][0][row], ml[3][0][row]));
        float L = 0.f;
#pragma unroll
        for (int w = 0; w < 4; ++w)
            L += ml[w][1][row] * EXP2(ml[w][0][row] - M);
        const float invL = 1.f / L;
        const int grow_ = gr0 + row;
#pragma unroll
        for (int j = 0; j < 4; ++j) {
            const int c = c0 + j * 4;
            f32x4 a = *(const f32x4*)&Obuf[0][row][c];
#pragma unroll
            for (int w = 1; w < 4; ++w) {
                const f32x4 b = *(const f32x4*)&Obuf[w][row][c];
                a[0] += b[0]; a[1] += b[1]; a[2] += b[2]; a[3] += b[3];
            }
            const float4 sc = *(const float4*)&Sc[(size_t)grow_ * D + c];
            float4 o;
            o.x = a[0] * invL + sc.x;
            o.y = a[1] * invL + sc.y;
            o.z = a[2] * invL + sc.z;
            o.w = a[3] * invL + sc.w;
            *(float4*)&out[(size_t)grow_ * D + c] = o;
        }
    }
}

extern "C" void kernel_launch(void* const* d_in, const int* in_sizes, int n_in,
                              void* d_out, int out_size, void* d_ws, size_t ws_size,
                              hipStream_t stream) {
    const float* x  = (const float*)d_in[0];
    const float* Wk = (const float*)d_in[1];
    const float* bk = (const float*)d_in[2];
    const float* Wq = (const float*)d_in[3];
    const float* bq = (const float*)d_in[4];
    const float* Wv = (const float*)d_in[5];
    const float* bv = (const float*)d_in[6];
    const float* Ws = (const float*)d_in[7];
    const float* bs = (const float*)d_in[8];
    float* out = (float*)d_out;

    u16*   Kh = (u16*)d_ws;                       // 4 MB fp16 (log2e-scaled)
    u16*   Qh = Kh + (size_t)BN * D;              // 4 MB fp16
    u16*   Vt = Qh + (size_t)BN * D;              // 4 MB fp16, [b][c][m]
    float* Sc = (float*)(Vt + (size_t)BN * D);    // 8 MB fp32
    u16*   Wt = (u16*)(Sc + (size_t)BN * D);      // 256 KB fp16 W^T (4 mats)

    prep_kernel<<<128, 256, 0, stream>>>(Wk, Wq, Wv, Ws, Wt);
    proj_kernel<<<dim3(128, 4), 256, 0, stream>>>(x, Wt, bk, bq, bv, bs,
                                                  Kh, Qh, Vt, Sc);
    attn_kernel<<<512, 256, 0, stream>>>(Kh, Qh, Vt, Sc, out);
}